// Round 5
// baseline (591.490 us; speedup 1.0000x reference)
//
#include <hip/hip_runtime.h>

#define N_NODES 50000
#define N_PAD   50048   // 391*128, GEMM drops all row guards
#define N_EDGES 800000
#define N_GRAPHS 512
#define F_IN 256
#define F_H 128
#define F_CAT 256

// bucketed CSR build
#define BSHIFT 9
#define NB 98           // ceil(50000/512) buckets
#define CAP 10240       // edge capacity per bucket (mean 8163, 23 sigma slack)
#define EPB 3125        // edges per scatter block (256 blocks)

typedef __attribute__((ext_vector_type(8))) short short8;
typedef __attribute__((ext_vector_type(4))) float f32x4;
typedef unsigned int uint;
typedef unsigned short ushort;

static __device__ __forceinline__ ushort f2bf(float f) {
    uint u = __float_as_uint(f);
    u += 0x7FFF + ((u >> 16) & 1);  // RNE
    return (ushort)(u >> 16);
}
static __device__ __forceinline__ float bflo(uint v) { return __uint_as_float(v << 16); }
static __device__ __forceinline__ float bfhi(uint v) { return __uint_as_float(v & 0xFFFF0000u); }

// async global->LDS, 16B per lane; lds base must be wave-uniform
#define GLL(g, l) __builtin_amdgcn_global_load_lds( \
    (const __attribute__((address_space(1))) unsigned int*)(g), \
    (__attribute__((address_space(3))) unsigned int*)(l), 16, 0, 0)

// ---------------------------------------------------------------------------
__global__ void init_gcur_kernel(int* gcur) {
    int t = threadIdx.x;
    if (t < 2 * NB) gcur[t] = (t % NB) * CAP;
}

// ---------------------------------------------------------------------------
// S1: bucket-scatter edges (block-local histogram + one global reserve/bucket)
__global__ __launch_bounds__(256) void csr_scatter_kernel(
        const int* __restrict__ ei, int* __restrict__ gcur,
        uint* __restrict__ ebuf_td, uint* __restrict__ ebuf_bu) {
    __shared__ int lcnt[256];   // [dir*128 + bucket]
    __shared__ int lbase[256];
    int tid = threadIdx.x;
    lcnt[tid] = 0;
    __syncthreads();
    int e0 = blockIdx.x * EPB;
    for (int k = tid; k < EPB; k += 256) {
        int i = e0 + k;
        int s = ei[i], d = ei[N_EDGES + i];
        atomicAdd(&lcnt[d >> BSHIFT], 1);
        atomicAdd(&lcnt[128 + (s >> BSHIFT)], 1);
    }
    __syncthreads();
    if (tid < 2 * NB) {
        int dir = tid / NB, b = tid % NB;
        int c = lcnt[dir * 128 + b];
        lbase[dir * 128 + b] = c ? atomicAdd(&gcur[dir * NB + b], c) : 0;
    }
    __syncthreads();
    lcnt[tid] = 0;
    __syncthreads();
    for (int k = tid; k < EPB; k += 256) {
        int i = e0 + k;
        int s = ei[i], d = ei[N_EDGES + i];
        int bd = d >> BSHIFT, bs = s >> BSHIFT;
        int p = atomicAdd(&lcnt[bd], 1) + lbase[bd];
        ebuf_td[p] = (uint)s | ((uint)(d & 511) << 16);
        int q = atomicAdd(&lcnt[128 + bs], 1) + lbase[128 + bs];
        ebuf_bu[q] = (uint)d | ((uint)(s & 511) << 16);
    }
}

// ---------------------------------------------------------------------------
// S2: per-(bucket,dir) CSR build, bucket-local scatter window
__global__ __launch_bounds__(256) void csr_build_kernel(
        const uint* __restrict__ ebuf_td, const uint* __restrict__ ebuf_bu,
        const int* __restrict__ gcur,
        int* off_td, int* off_bu, ushort* deg_td, ushort* deg_bu,
        float* dinv_td, float* dinv_bu, ushort* csr_td, ushort* csr_bu) {
    int b = blockIdx.x, dir = blockIdx.y;
    const uint* ebuf = dir ? ebuf_bu : ebuf_td;
    int* off     = dir ? off_bu : off_td;
    ushort* deg  = dir ? deg_bu : deg_td;
    float* dinv  = dir ? dinv_bu : dinv_td;
    ushort* csr  = dir ? csr_bu : csr_td;
    __shared__ int cntL[512], offL[512], sm[256];
    int tid = threadIdx.x;
    cntL[tid] = 0; cntL[tid + 256] = 0;
    __syncthreads();
    int rbeg = b * CAP;
    int rend = gcur[dir * NB + b];
    for (int k = rbeg + tid; k < rend; k += 256)
        atomicAdd(&cntL[ebuf[k] >> 16], 1);
    __syncthreads();
    int a0 = cntL[tid * 2], a1 = cntL[tid * 2 + 1];
    int ps = a0 + a1;
    sm[tid] = ps;
    __syncthreads();
    for (int o = 1; o < 256; o <<= 1) {
        int u = (tid >= o) ? sm[tid - o] : 0;
        __syncthreads();
        sm[tid] += u;
        __syncthreads();
    }
    int excl = sm[tid] - ps;
    offL[tid * 2] = excl;
    offL[tid * 2 + 1] = excl + a0;
    __syncthreads();
    int nbase = b << BSHIFT;
#pragma unroll
    for (int j = 0; j < 2; j++) {
        int nloc = tid + j * 256;
        int n = nbase + nloc;
        if (n < N_NODES) {
            off[n] = rbeg + offL[nloc];
            int c = cntL[nloc];
            deg[n] = (ushort)c;
            dinv[n] = rsqrtf((float)c + 1.0f);
        }
    }
    cntL[tid] = offL[tid];
    cntL[tid + 256] = offL[tid + 256];
    __syncthreads();
    for (int k = rbeg + tid; k < rend; k += 256) {
        uint e = ebuf[k];
        int slot = atomicAdd(&cntL[e >> 16], 1);
        csr[rbeg + slot] = (ushort)(e & 0xFFFF);
    }
}

// ---------------------------------------------------------------------------
__global__ void cvt_x_kernel(const float* __restrict__ x, ushort* __restrict__ xb) {
    size_t i = (size_t)blockIdx.x * blockDim.x + threadIdx.x;  // float4 index
    ushort4 u = {0, 0, 0, 0};
    if (i < (size_t)N_NODES * (F_IN / 4)) {
        float4 f = ((const float4*)x)[i];
        u.x = f2bf(f.x); u.y = f2bf(f.y); u.z = f2bf(f.z); u.w = f2bf(f.w);
    }
    ((ushort4*)xb)[i] = u;
}

// ---------------------------------------------------------------------------
__global__ void prep_w_kernel(const float* __restrict__ td_W1, const float* __restrict__ bu_W1,
                              const float* __restrict__ td_W2, const float* __restrict__ bu_W2,
                              ushort* __restrict__ Bt1, ushort* __restrict__ Bt2) {
    int n = blockIdx.x;
    int k = threadIdx.x;
    float w1 = (n < F_H) ? td_W1[(size_t)k * F_H + n] : bu_W1[(size_t)k * F_H + (n - F_H)];
    Bt1[(size_t)n * 256 + k] = f2bf(w1);
    if (k < 128) {
        float w2 = (n < F_H) ? td_W2[(size_t)k * F_H + n]
                             : bu_W2[(size_t)k * F_H + (n - F_H)];
        Bt2[(size_t)n * 128 + k] = f2bf(w2);
    }
}

// ---------------------------------------------------------------------------
// MFMA GEMM, global_load_lds staging. 128x128 tile, BK=32, 256 thr / 4 waves.
__global__ __launch_bounds__(256) void gemm_mfma(
        const ushort* __restrict__ A, const ushort* __restrict__ Bt,
        ushort* __restrict__ C,
        const float* __restrict__ dinv_td, const float* __restrict__ dinv_bu,
        int kLen, int ldb, int aSplit) {
    __shared__ __align__(16) ushort As[128 * 32];
    __shared__ __align__(16) ushort Bs[128 * 32];
    int tid = threadIdx.x;
    int wave = tid >> 6, lane = tid & 63, quad = lane >> 4, l16 = lane & 15;
    size_t bm = (size_t)blockIdx.x * 128;
    size_t bn = (size_t)blockIdx.y * 128;
    const float* dsel = blockIdx.y ? dinv_bu : dinv_td;
    int aOff = aSplit ? (int)bn : 0;

    f32x4 acc[2][8];
    const f32x4 z4 = {0.f, 0.f, 0.f, 0.f};
#pragma unroll
    for (int i = 0; i < 2; i++)
#pragma unroll
        for (int j = 0; j < 8; j++) acc[i][j] = z4;

    int cb0 = wave * 64;
    int cb1 = 256 + wave * 64;
    int c0 = cb0 + lane, c1 = cb1 + lane;
    int r0 = c0 >> 2, s0 = (c0 & 3) * 8;
    int r1 = c1 >> 2, s1 = (c1 & 3) * 8;
    const ushort* a0p = A + (bm + r0) * 256 + aOff + s0;
    const ushort* a1p = A + (bm + r1) * 256 + aOff + s1;
    const ushort* b0p = Bt + (bn + r0) * ldb + s0;
    const ushort* b1p = Bt + (bn + r1) * ldb + s1;
    ushort* lA0 = As + cb0 * 8;
    ushort* lA1 = As + cb1 * 8;
    ushort* lB0 = Bs + cb0 * 8;
    ushort* lB1 = Bs + cb1 * 8;

    int nkb = kLen >> 5;
    for (int kb = 0; kb < nkb; kb++) {
        int k0 = kb * 32;
        __syncthreads();
        GLL(a0p + k0, lA0);
        GLL(a1p + k0, lA1);
        GLL(b0p + k0, lB0);
        GLL(b1p + k0, lB1);
        __syncthreads();
        short8 af0 = *(const short8*)(As + (wave * 32 + l16) * 32 + quad * 8);
        short8 af1 = *(const short8*)(As + (wave * 32 + 16 + l16) * 32 + quad * 8);
#pragma unroll
        for (int ct = 0; ct < 8; ct++) {
            short8 bfr = *(const short8*)(Bs + (ct * 16 + l16) * 32 + quad * 8);
            acc[0][ct] = __builtin_amdgcn_mfma_f32_16x16x32_bf16(af0, bfr, acc[0][ct], 0, 0, 0);
            acc[1][ct] = __builtin_amdgcn_mfma_f32_16x16x32_bf16(af1, bfr, acc[1][ct], 0, 0, 0);
        }
    }
#pragma unroll
    for (int rt = 0; rt < 2; rt++) {
#pragma unroll
        for (int r = 0; r < 4; r++) {
            size_t row = bm + wave * 32 + rt * 16 + quad * 4 + r;
            float dv = dsel[row];
#pragma unroll
            for (int ct = 0; ct < 8; ct++) {
                C[row * 256 + bn + ct * 16 + l16] = f2bf(acc[rt][ct][r] * dv);
            }
        }
    }
}

// ---------------------------------------------------------------------------
// XCD-sliced layer-1 aggregation. Slice s = blockIdx.x & 7 owns cols
// [32s, 32s+32) (64 B/row -> one line). dir = s>>2 (td: s<4, bu: s>=4).
// One wave per node; lane = e_sub*16 + c_sub: 4 edges x 16 col-pairs per
// gather. Neighbor partials reduced via shfl_xor(16/32).
__global__ __launch_bounds__(256) void agg1_kernel(
        const ushort* __restrict__ linS, ushort* __restrict__ h1b,
        const ushort* __restrict__ csr_td, const int* __restrict__ off_td,
        const ushort* __restrict__ deg_td, const float* __restrict__ dinv_td,
        const ushort* __restrict__ csr_bu, const int* __restrict__ off_bu,
        const ushort* __restrict__ deg_bu, const float* __restrict__ dinv_bu,
        const float* __restrict__ b_td, const float* __restrict__ b_bu) {
    int s = blockIdx.x & 7;
    int wave = threadIdx.x >> 6, lane = threadIdx.x & 63;
    int n = (blockIdx.x >> 3) * 4 + wave;  // grid sized so n < N_NODES
    int dir = s >> 2;
    const ushort* csr = dir ? csr_bu : csr_td;
    const int* off    = dir ? off_bu : off_td;
    const ushort* deg = dir ? deg_bu : deg_td;
    const float* dinv = dir ? dinv_bu : dinv_td;
    const float* bias = dir ? b_bu : b_td;
    int e_sub = lane >> 4, c_sub = lane & 15;
    int col = s * 32 + c_sub * 2;
    const ushort* base = linS + col;

    float a0 = 0.f, a1 = 0.f;
    int kb = off[n], ke = kb + deg[n];
    for (int k = kb; k < ke; k += 8) {
        int k1 = k + e_sub, k2 = k + 4 + e_sub;
        uint v1 = 0, v2 = 0;
        if (k1 < ke) v1 = *(const uint*)(base + (size_t)csr[k1] * F_CAT);
        if (k2 < ke) v2 = *(const uint*)(base + (size_t)csr[k2] * F_CAT);
        a0 += bflo(v1) + bflo(v2);
        a1 += bfhi(v1) + bfhi(v2);
    }
    a0 += __shfl_xor(a0, 16); a1 += __shfl_xor(a1, 16);
    a0 += __shfl_xor(a0, 32); a1 += __shfl_xor(a1, 32);
    uint vs = *(const uint*)(base + (size_t)n * F_CAT);  // self loop
    a0 += bflo(vs); a1 += bfhi(vs);
    float dn = dinv[n];
    int bcol = col - dir * F_H;
    float o0 = fmaxf(a0 * dn + bias[bcol], 0.f);
    float o1 = fmaxf(a1 * dn + bias[bcol + 1], 0.f);
    if (e_sub == 0) {
        uint pk = (uint)f2bf(o0) | ((uint)f2bf(o1) << 16);
        *(uint*)(h1b + (size_t)n * F_CAT + col) = pk;
    }
}

// ---------------------------------------------------------------------------
// XCD-sliced layer-2 aggregation + global_add_pool. One wave = 8 consecutive
// nodes of one slice; sorted batch -> per-graph segment accumulate, flush
// with 16-lane atomic pairs. pooled = concat([bu, td]) -> pcol swaps halves.
__global__ __launch_bounds__(256) void agg2_pool_kernel(
        const ushort* __restrict__ linS, float* __restrict__ pooled,
        const int* __restrict__ batch,
        const ushort* __restrict__ csr_td, const int* __restrict__ off_td,
        const ushort* __restrict__ deg_td, const float* __restrict__ dinv_td,
        const ushort* __restrict__ csr_bu, const int* __restrict__ off_bu,
        const ushort* __restrict__ deg_bu, const float* __restrict__ dinv_bu,
        const float* __restrict__ b_td, const float* __restrict__ b_bu) {
    int s = blockIdx.x & 7;
    int wave = threadIdx.x >> 6, lane = threadIdx.x & 63;
    int n0 = ((blockIdx.x >> 3) * 4 + wave) * 8;
    if (n0 >= N_NODES) return;  // wave-uniform
    int dir = s >> 2;
    const ushort* csr = dir ? csr_bu : csr_td;
    const int* off    = dir ? off_bu : off_td;
    const ushort* deg = dir ? deg_bu : deg_td;
    const float* dinv = dir ? dinv_bu : dinv_td;
    const float* bias = dir ? b_bu : b_td;
    int e_sub = lane >> 4, c_sub = lane & 15;
    int col = s * 32 + c_sub * 2;
    int pcol = ((s + 4) & 7) * 32 + c_sub * 2;
    const ushort* base = linS + col;
    int bcol = col - dir * F_H;
    float bs0 = bias[bcol], bs1 = bias[bcol + 1];

    float acc0 = 0.f, acc1 = 0.f;
    int gcur = batch[n0];
#pragma unroll
    for (int j = 0; j < 8; j++) {
        int n = n0 + j;
        int g = batch[n];
        if (g != gcur) {  // wave-uniform
            if (e_sub == 0) {
                unsafeAtomicAdd(&pooled[(size_t)gcur * F_CAT + pcol], acc0);
                unsafeAtomicAdd(&pooled[(size_t)gcur * F_CAT + pcol + 1], acc1);
            }
            acc0 = acc1 = 0.f;
            gcur = g;
        }
        float a0 = 0.f, a1 = 0.f;
        int kb = off[n], ke = kb + deg[n];
        for (int k = kb; k < ke; k += 8) {
            int k1 = k + e_sub, k2 = k + 4 + e_sub;
            uint v1 = 0, v2 = 0;
            if (k1 < ke) v1 = *(const uint*)(base + (size_t)csr[k1] * F_CAT);
            if (k2 < ke) v2 = *(const uint*)(base + (size_t)csr[k2] * F_CAT);
            a0 += bflo(v1) + bflo(v2);
            a1 += bfhi(v1) + bfhi(v2);
        }
        a0 += __shfl_xor(a0, 16); a1 += __shfl_xor(a1, 16);
        a0 += __shfl_xor(a0, 32); a1 += __shfl_xor(a1, 32);
        uint vs = *(const uint*)(base + (size_t)n * F_CAT);
        a0 += bflo(vs); a1 += bfhi(vs);
        float dn = dinv[n];
        acc0 += a0 * dn + bs0;
        acc1 += a1 * dn + bs1;
    }
    if (e_sub == 0) {
        unsafeAtomicAdd(&pooled[(size_t)gcur * F_CAT + pcol], acc0);
        unsafeAtomicAdd(&pooled[(size_t)gcur * F_CAT + pcol + 1], acc1);
    }
}

// ---------------------------------------------------------------------------
__global__ __launch_bounds__(256) void mlp_kernel(const float* __restrict__ pooled,
                                                  const float* __restrict__ pw1,
                                                  const float* __restrict__ pb1,
                                                  const float* __restrict__ pw2,
                                                  const float* __restrict__ pb2,
                                                  float* __restrict__ out) {
    int g = blockIdx.x;
    int tid = threadIdx.x;
    __shared__ float row[256];
    __shared__ float hid[256];
    row[tid] = pooled[(size_t)g * 256 + tid];
    __syncthreads();
    float acc = pb1[tid];
    for (int k = 0; k < 256; k++) acc += row[k] * pw1[(size_t)k * 256 + tid];
    hid[tid] = fmaxf(acc, 0.f);
    __syncthreads();
    if (tid < 128) {
        float o = pb2[tid];
        for (int k = 0; k < 256; k++) o += hid[k] * pw2[(size_t)k * 128 + tid];
        out[(size_t)g * 128 + tid] = o;
    }
}

// ---------------------------------------------------------------------------
extern "C" void kernel_launch(void* const* d_in, const int* in_sizes, int n_in,
                              void* d_out, int out_size, void* d_ws, size_t ws_size,
                              hipStream_t stream) {
    const float* x     = (const float*)d_in[0];
    const int*   ei    = (const int*)d_in[1];
    const int*   batch = (const int*)d_in[2];
    const float* td_W1 = (const float*)d_in[4];
    const float* td_b1 = (const float*)d_in[5];
    const float* td_W2 = (const float*)d_in[6];
    const float* td_b2 = (const float*)d_in[7];
    const float* bu_W1 = (const float*)d_in[8];
    const float* bu_b1 = (const float*)d_in[9];
    const float* bu_W2 = (const float*)d_in[10];
    const float* bu_b2 = (const float*)d_in[11];
    const float* pw1   = (const float*)d_in[12];
    const float* pb1   = (const float*)d_in[13];
    const float* pw2   = (const float*)d_in[14];
    const float* pb2   = (const float*)d_in[15];
    float* out = (float*)d_out;

    // ---- workspace carve ----
    char* p = (char*)d_ws;
    auto alloc = [&](size_t bytes) { void* r = (void*)p; p += (bytes + 255) & ~(size_t)255; return r; };
    int* gcur = (int*)alloc(2 * NB * sizeof(int));
    uint* ebuf_td = (uint*)alloc((size_t)NB * CAP * sizeof(uint));
    uint* ebuf_bu = (uint*)alloc((size_t)NB * CAP * sizeof(uint));
    ushort* csr_td = (ushort*)alloc((size_t)NB * CAP * sizeof(ushort));
    ushort* csr_bu = (ushort*)alloc((size_t)NB * CAP * sizeof(ushort));
    int* off_td = (int*)alloc((size_t)N_NODES * sizeof(int));
    int* off_bu = (int*)alloc((size_t)N_NODES * sizeof(int));
    ushort* deg_td = (ushort*)alloc((size_t)N_NODES * sizeof(ushort));
    ushort* deg_bu = (ushort*)alloc((size_t)N_NODES * sizeof(ushort));
    float* dinv_td = (float*)alloc((size_t)N_PAD * sizeof(float));
    float* dinv_bu = (float*)alloc((size_t)N_PAD * sizeof(float));
    ushort* Bt1 = (ushort*)alloc((size_t)256 * 256 * sizeof(ushort));
    ushort* Bt2 = (ushort*)alloc((size_t)256 * 128 * sizeof(ushort));
    ushort* xb   = (ushort*)alloc((size_t)N_PAD * F_CAT * sizeof(ushort));
    ushort* linb = (ushort*)alloc((size_t)N_PAD * F_CAT * sizeof(ushort));
    ushort* h1b  = (ushort*)alloc((size_t)N_PAD * F_CAT * sizeof(ushort));
    float* pooled = (float*)alloc((size_t)N_GRAPHS * F_CAT * sizeof(float));  // memset

    hipMemsetAsync(pooled, 0, (size_t)N_GRAPHS * F_CAT * sizeof(float), stream);

    // ---- graph structure (bucketed counting sort) ----
    init_gcur_kernel<<<1, 256, 0, stream>>>(gcur);
    csr_scatter_kernel<<<N_EDGES / EPB, 256, 0, stream>>>(ei, gcur, ebuf_td, ebuf_bu);
    csr_build_kernel<<<dim3(NB, 2), 256, 0, stream>>>(ebuf_td, ebuf_bu, gcur,
        off_td, off_bu, deg_td, deg_bu, dinv_td, dinv_bu, csr_td, csr_bu);

    // ---- bf16 conversions ----
    cvt_x_kernel<<<(N_PAD * F_IN / 4) / 256, 256, 0, stream>>>(x, xb);
    prep_w_kernel<<<256, 256, 0, stream>>>(td_W1, bu_W1, td_W2, bu_W2, Bt1, Bt2);

    dim3 gg(N_PAD / 128, 2);

    // ---- layer 1 ----
    gemm_mfma<<<gg, 256, 0, stream>>>(xb, Bt1, linb, dinv_td, dinv_bu, 256, 256, 0);
    agg1_kernel<<<(N_NODES / 4) * 8, 256, 0, stream>>>(linb, h1b,
        csr_td, off_td, deg_td, dinv_td, csr_bu, off_bu, deg_bu, dinv_bu, td_b1, bu_b1);

    // ---- layer 2 (block-diagonal -> K=128 split) + pool ----
    gemm_mfma<<<gg, 256, 0, stream>>>(h1b, Bt2, linb, dinv_td, dinv_bu, 128, 128, 1);
    agg2_pool_kernel<<<((N_NODES / 8 + 3) / 4) * 8, 256, 0, stream>>>(linb, pooled, batch,
        csr_td, off_td, deg_td, dinv_td, csr_bu, off_bu, deg_bu, dinv_bu, td_b2, bu_b2);

    // ---- projection head ----
    mlp_kernel<<<N_GRAPHS, 256, 0, stream>>>(pooled, pw1, pb1, pw2, pb2, out);
}

// Round 6
// 360.874 us; speedup vs baseline: 1.6390x; 1.6390x over previous
//
#include <hip/hip_runtime.h>

#define N_NODES 50000
#define N_PAD   50048   // 391*128, GEMM drops all row guards
#define N_EDGES 800000
#define N_GRAPHS 512
#define F_IN 256
#define F_H 128
#define F_CAT 256

// bucketed CSR build
#define BSHIFT 9
#define NB 98           // ceil(50000/512) buckets
#define CAP 10240       // edge capacity per bucket (mean 8163, 23 sigma slack)
#define EPB 3125        // edges per scatter block (256 blocks)

typedef __attribute__((ext_vector_type(8))) short short8;
typedef __attribute__((ext_vector_type(4))) float f32x4;
typedef unsigned int uint;
typedef unsigned short ushort;

static __device__ __forceinline__ ushort f2bf(float f) {
    uint u = __float_as_uint(f);
    u += 0x7FFF + ((u >> 16) & 1);  // RNE
    return (ushort)(u >> 16);
}
static __device__ __forceinline__ float bflo(uint v) { return __uint_as_float(v << 16); }
static __device__ __forceinline__ float bfhi(uint v) { return __uint_as_float(v & 0xFFFF0000u); }

// async global->LDS, 16B per lane; lds base must be wave-uniform
#define GLL(g, l) __builtin_amdgcn_global_load_lds( \
    (const __attribute__((address_space(1))) unsigned int*)(g), \
    (__attribute__((address_space(3))) unsigned int*)(l), 16, 0, 0)

// ---------------------------------------------------------------------------
// S1: bucket-scatter edges. gcur is RELATIVE (zero-initialized by memset).
__global__ __launch_bounds__(256) void csr_scatter_kernel(
        const int* __restrict__ ei, int* __restrict__ gcur,
        uint* __restrict__ ebuf_td, uint* __restrict__ ebuf_bu) {
    __shared__ int lcnt[256];   // [dir*128 + bucket]
    __shared__ int lbase[256];
    int tid = threadIdx.x;
    lcnt[tid] = 0;
    __syncthreads();
    int e0 = blockIdx.x * EPB;
    for (int k = tid; k < EPB; k += 256) {
        int i = e0 + k;
        int s = ei[i], d = ei[N_EDGES + i];
        atomicAdd(&lcnt[d >> BSHIFT], 1);
        atomicAdd(&lcnt[128 + (s >> BSHIFT)], 1);
    }
    __syncthreads();
    if (tid < 2 * NB) {
        int dir = tid / NB, b = tid % NB;
        int c = lcnt[dir * 128 + b];
        lbase[dir * 128 + b] = c ? atomicAdd(&gcur[dir * NB + b], c) : 0;
    }
    __syncthreads();
    lcnt[tid] = 0;
    __syncthreads();
    for (int k = tid; k < EPB; k += 256) {
        int i = e0 + k;
        int s = ei[i], d = ei[N_EDGES + i];
        int bd = d >> BSHIFT, bs = s >> BSHIFT;
        int p = atomicAdd(&lcnt[bd], 1) + lbase[bd];
        ebuf_td[(size_t)bd * CAP + p] = (uint)s | ((uint)(d & 511) << 16);
        int q = atomicAdd(&lcnt[128 + bs], 1) + lbase[128 + bs];
        ebuf_bu[(size_t)bs * CAP + q] = (uint)d | ((uint)(s & 511) << 16);
    }
}

// ---------------------------------------------------------------------------
// S2: per-(bucket,dir) CSR build, bucket-local scatter window
__global__ __launch_bounds__(256) void csr_build_kernel(
        const uint* __restrict__ ebuf_td, const uint* __restrict__ ebuf_bu,
        const int* __restrict__ gcur,
        int* off_td, int* off_bu, ushort* deg_td, ushort* deg_bu,
        float* dinv_td, float* dinv_bu, ushort* csr_td, ushort* csr_bu) {
    int b = blockIdx.x, dir = blockIdx.y;
    const uint* ebuf = dir ? ebuf_bu : ebuf_td;
    int* off     = dir ? off_bu : off_td;
    ushort* deg  = dir ? deg_bu : deg_td;
    float* dinv  = dir ? dinv_bu : dinv_td;
    ushort* csr  = dir ? csr_bu : csr_td;
    __shared__ int cntL[512], offL[512], sm[256];
    int tid = threadIdx.x;
    cntL[tid] = 0; cntL[tid + 256] = 0;
    __syncthreads();
    int rbeg = b * CAP;
    int rend = rbeg + gcur[dir * NB + b];
    for (int k = rbeg + tid; k < rend; k += 256)
        atomicAdd(&cntL[ebuf[k] >> 16], 1);
    __syncthreads();
    int a0 = cntL[tid * 2], a1 = cntL[tid * 2 + 1];
    int ps = a0 + a1;
    sm[tid] = ps;
    __syncthreads();
    for (int o = 1; o < 256; o <<= 1) {
        int u = (tid >= o) ? sm[tid - o] : 0;
        __syncthreads();
        sm[tid] += u;
        __syncthreads();
    }
    int excl = sm[tid] - ps;
    offL[tid * 2] = excl;
    offL[tid * 2 + 1] = excl + a0;
    __syncthreads();
    int nbase = b << BSHIFT;
#pragma unroll
    for (int j = 0; j < 2; j++) {
        int nloc = tid + j * 256;
        int n = nbase + nloc;
        if (n < N_NODES) {
            off[n] = rbeg + offL[nloc];
            int c = cntL[nloc];
            deg[n] = (ushort)c;
            dinv[n] = rsqrtf((float)c + 1.0f);
        }
    }
    cntL[tid] = offL[tid];
    cntL[tid + 256] = offL[tid + 256];
    __syncthreads();
    for (int k = rbeg + tid; k < rend; k += 256) {
        uint e = ebuf[k];
        int slot = atomicAdd(&cntL[e >> 16], 1);
        csr[rbeg + slot] = (ushort)(e & 0xFFFF);
    }
}

// ---------------------------------------------------------------------------
__global__ void cvt_x_kernel(const float* __restrict__ x, ushort* __restrict__ xb) {
    size_t i = (size_t)blockIdx.x * blockDim.x + threadIdx.x;  // float4 index
    ushort4 u = {0, 0, 0, 0};
    if (i < (size_t)N_NODES * (F_IN / 4)) {
        float4 f = ((const float4*)x)[i];
        u.x = f2bf(f.x); u.y = f2bf(f.y); u.z = f2bf(f.z); u.w = f2bf(f.w);
    }
    ((ushort4*)xb)[i] = u;
}

// ---------------------------------------------------------------------------
__global__ void prep_w_kernel(const float* __restrict__ td_W1, const float* __restrict__ bu_W1,
                              const float* __restrict__ td_W2, const float* __restrict__ bu_W2,
                              ushort* __restrict__ Bt1, ushort* __restrict__ Bt2) {
    int n = blockIdx.x;
    int k = threadIdx.x;
    float w1 = (n < F_H) ? td_W1[(size_t)k * F_H + n] : bu_W1[(size_t)k * F_H + (n - F_H)];
    Bt1[(size_t)n * 256 + k] = f2bf(w1);
    if (k < 128) {
        float w2 = (n < F_H) ? td_W2[(size_t)k * F_H + n]
                             : bu_W2[(size_t)k * F_H + (n - F_H)];
        Bt2[(size_t)n * 128 + k] = f2bf(w2);
    }
}

// ---------------------------------------------------------------------------
// MFMA GEMM, global_load_lds staging. 128x128 tile, BK=32, 256 thr / 4 waves.
__global__ __launch_bounds__(256) void gemm_mfma(
        const ushort* __restrict__ A, const ushort* __restrict__ Bt,
        ushort* __restrict__ C,
        const float* __restrict__ dinv_td, const float* __restrict__ dinv_bu,
        int kLen, int ldb, int aSplit) {
    __shared__ __align__(16) ushort As[128 * 32];
    __shared__ __align__(16) ushort Bs[128 * 32];
    int tid = threadIdx.x;
    int wave = tid >> 6, lane = tid & 63, quad = lane >> 4, l16 = lane & 15;
    size_t bm = (size_t)blockIdx.x * 128;
    size_t bn = (size_t)blockIdx.y * 128;
    const float* dsel = blockIdx.y ? dinv_bu : dinv_td;
    int aOff = aSplit ? (int)bn : 0;

    f32x4 acc[2][8];
    const f32x4 z4 = {0.f, 0.f, 0.f, 0.f};
#pragma unroll
    for (int i = 0; i < 2; i++)
#pragma unroll
        for (int j = 0; j < 8; j++) acc[i][j] = z4;

    int cb0 = wave * 64;
    int cb1 = 256 + wave * 64;
    int c0 = cb0 + lane, c1 = cb1 + lane;
    int r0 = c0 >> 2, s0 = (c0 & 3) * 8;
    int r1 = c1 >> 2, s1 = (c1 & 3) * 8;
    const ushort* a0p = A + (bm + r0) * 256 + aOff + s0;
    const ushort* a1p = A + (bm + r1) * 256 + aOff + s1;
    const ushort* b0p = Bt + (bn + r0) * ldb + s0;
    const ushort* b1p = Bt + (bn + r1) * ldb + s1;
    ushort* lA0 = As + cb0 * 8;
    ushort* lA1 = As + cb1 * 8;
    ushort* lB0 = Bs + cb0 * 8;
    ushort* lB1 = Bs + cb1 * 8;

    int nkb = kLen >> 5;
    for (int kb = 0; kb < nkb; kb++) {
        int k0 = kb * 32;
        __syncthreads();
        GLL(a0p + k0, lA0);
        GLL(a1p + k0, lA1);
        GLL(b0p + k0, lB0);
        GLL(b1p + k0, lB1);
        __syncthreads();
        short8 af0 = *(const short8*)(As + (wave * 32 + l16) * 32 + quad * 8);
        short8 af1 = *(const short8*)(As + (wave * 32 + 16 + l16) * 32 + quad * 8);
#pragma unroll
        for (int ct = 0; ct < 8; ct++) {
            short8 bfr = *(const short8*)(Bs + (ct * 16 + l16) * 32 + quad * 8);
            acc[0][ct] = __builtin_amdgcn_mfma_f32_16x16x32_bf16(af0, bfr, acc[0][ct], 0, 0, 0);
            acc[1][ct] = __builtin_amdgcn_mfma_f32_16x16x32_bf16(af1, bfr, acc[1][ct], 0, 0, 0);
        }
    }
#pragma unroll
    for (int rt = 0; rt < 2; rt++) {
#pragma unroll
        for (int r = 0; r < 4; r++) {
            size_t row = bm + wave * 32 + rt * 16 + quad * 4 + r;
            float dv = dsel[row];
#pragma unroll
            for (int ct = 0; ct < 8; ct++) {
                C[row * 256 + bn + ct * 16 + l16] = f2bf(acc[rt][ct][r] * dv);
            }
        }
    }
}

// ---------------------------------------------------------------------------
// Wave-gather core: lane = half*32 + l32; l32 covers 4 cols (uint2), half
// selects one of 2 concurrent edge rows. Unroll-4 -> 8 edges in flight.
// Accumulates neighbor sum into a[0..3] (cols l32*4 .. l32*4+3).
static __device__ __forceinline__ void gather_node(
        const ushort* __restrict__ base, const ushort* __restrict__ csr,
        int kb, int ke, int half, float a[4]) {
    float p[4] = {0.f, 0.f, 0.f, 0.f};
    float q[4] = {0.f, 0.f, 0.f, 0.f};
    float r[4] = {0.f, 0.f, 0.f, 0.f};
    int k = kb;
    for (; k + 8 <= ke; k += 8) {
        int i0 = csr[k + half];
        int i1 = csr[k + 2 + half];
        int i2 = csr[k + 4 + half];
        int i3 = csr[k + 6 + half];
        uint2 v0 = *(const uint2*)(base + (size_t)i0 * F_CAT);
        uint2 v1 = *(const uint2*)(base + (size_t)i1 * F_CAT);
        uint2 v2 = *(const uint2*)(base + (size_t)i2 * F_CAT);
        uint2 v3 = *(const uint2*)(base + (size_t)i3 * F_CAT);
        a[0] += bflo(v0.x); a[1] += bfhi(v0.x); a[2] += bflo(v0.y); a[3] += bfhi(v0.y);
        p[0] += bflo(v1.x); p[1] += bfhi(v1.x); p[2] += bflo(v1.y); p[3] += bfhi(v1.y);
        q[0] += bflo(v2.x); q[1] += bfhi(v2.x); q[2] += bflo(v2.y); q[3] += bfhi(v2.y);
        r[0] += bflo(v3.x); r[1] += bfhi(v3.x); r[2] += bflo(v3.y); r[3] += bfhi(v3.y);
    }
    for (; k < ke; k += 2) {
        int kk = k + half;
        if (kk < ke) {
            uint2 v = *(const uint2*)(base + (size_t)csr[kk] * F_CAT);
            a[0] += bflo(v.x); a[1] += bfhi(v.x); a[2] += bflo(v.y); a[3] += bfhi(v.y);
        }
    }
#pragma unroll
    for (int j = 0; j < 4; j++) a[j] += (p[j] + q[j]) + r[j];
}

// ---------------------------------------------------------------------------
// Layer-1 aggregation. 256 thr = 4 waves; wave w: node blockIdx*2+(w>>1),
// branch w&1. relu(dn*(self+neigh)+b) -> bf16 h1.
__global__ __launch_bounds__(256) void agg1_kernel(
        const ushort* __restrict__ linS, ushort* __restrict__ h1b,
        const ushort* __restrict__ csr_td, const int* __restrict__ off_td,
        const ushort* __restrict__ deg_td, const float* __restrict__ dinv_td,
        const ushort* __restrict__ csr_bu, const int* __restrict__ off_bu,
        const ushort* __restrict__ deg_bu, const float* __restrict__ dinv_bu,
        const float* __restrict__ b_td, const float* __restrict__ b_bu) {
    int wave = threadIdx.x >> 6, lane = threadIdx.x & 63;
    int n = blockIdx.x * 2 + (wave >> 1);
    int br = wave & 1;
    const ushort* csr = br ? csr_bu : csr_td;
    const int* off    = br ? off_bu : off_td;
    const ushort* deg = br ? deg_bu : deg_td;
    const float* dinv = br ? dinv_bu : dinv_td;
    const float* bias = br ? b_bu : b_td;
    int half = lane >> 5, l32 = lane & 31;
    int col = br * F_H + l32 * 4;
    const ushort* base = linS + col;

    float a[4] = {0.f, 0.f, 0.f, 0.f};
    int kb = off[n];
    gather_node(base, csr, kb, kb + deg[n], half, a);
#pragma unroll
    for (int j = 0; j < 4; j++) a[j] += __shfl_xor(a[j], 32);
    uint2 vs = *(const uint2*)(base + (size_t)n * F_CAT);  // self loop
    a[0] += bflo(vs.x); a[1] += bfhi(vs.x); a[2] += bflo(vs.y); a[3] += bfhi(vs.y);
    float dn = dinv[n];
    int bcol = l32 * 4;
    float o0 = fmaxf(a[0] * dn + bias[bcol],     0.f);
    float o1 = fmaxf(a[1] * dn + bias[bcol + 1], 0.f);
    float o2 = fmaxf(a[2] * dn + bias[bcol + 2], 0.f);
    float o3 = fmaxf(a[3] * dn + bias[bcol + 3], 0.f);
    if (half == 0) {
        uint2 pk;
        pk.x = (uint)f2bf(o0) | ((uint)f2bf(o1) << 16);
        pk.y = (uint)f2bf(o2) | ((uint)f2bf(o3) << 16);
        *(uint2*)(h1b + (size_t)n * F_CAT + col) = pk;
    }
}

// ---------------------------------------------------------------------------
// Layer-2 aggregation fused with global_add_pool. Wave handles 8 consecutive
// nodes of one branch; sorted batch -> segment accumulate + atomic flush.
// pooled = concat([bu, td]): td (br=0) -> cols 128.., bu (br=1) -> cols 0..
__global__ __launch_bounds__(256) void agg2_pool_kernel(
        const ushort* __restrict__ linS, float* __restrict__ pooled,
        const int* __restrict__ batch,
        const ushort* __restrict__ csr_td, const int* __restrict__ off_td,
        const ushort* __restrict__ deg_td, const float* __restrict__ dinv_td,
        const ushort* __restrict__ csr_bu, const int* __restrict__ off_bu,
        const ushort* __restrict__ deg_bu, const float* __restrict__ dinv_bu,
        const float* __restrict__ b_td, const float* __restrict__ b_bu) {
    int wave = threadIdx.x >> 6, lane = threadIdx.x & 63;
    int n0 = (blockIdx.x * 2 + (wave >> 1)) * 8;
    int br = wave & 1;
    const ushort* csr = br ? csr_bu : csr_td;
    const int* off    = br ? off_bu : off_td;
    const ushort* deg = br ? deg_bu : deg_td;
    const float* dinv = br ? dinv_bu : dinv_td;
    const float* bias = br ? b_bu : b_td;
    int half = lane >> 5, l32 = lane & 31;
    int col = br * F_H + l32 * 4;
    int pcol = (br ? 0 : F_H) + l32 * 4;
    const ushort* base = linS + col;
    int bcol = l32 * 4;
    float bs0 = bias[bcol], bs1 = bias[bcol + 1];
    float bs2 = bias[bcol + 2], bs3 = bias[bcol + 3];

    float acc0 = 0.f, acc1 = 0.f, acc2 = 0.f, acc3 = 0.f;
    int gcur = batch[n0];
#pragma unroll
    for (int j = 0; j < 8; j++) {
        int n = n0 + j;
        int g = batch[n];
        if (g != gcur) {  // wave-uniform
            if (half == 0) {
                float* pp = &pooled[(size_t)gcur * F_CAT + pcol];
                unsafeAtomicAdd(pp,     acc0);
                unsafeAtomicAdd(pp + 1, acc1);
                unsafeAtomicAdd(pp + 2, acc2);
                unsafeAtomicAdd(pp + 3, acc3);
            }
            acc0 = acc1 = acc2 = acc3 = 0.f;
            gcur = g;
        }
        float a[4] = {0.f, 0.f, 0.f, 0.f};
        int kb = off[n];
        gather_node(base, csr, kb, kb + deg[n], half, a);
#pragma unroll
        for (int t = 0; t < 4; t++) a[t] += __shfl_xor(a[t], 32);
        uint2 vs = *(const uint2*)(base + (size_t)n * F_CAT);
        a[0] += bflo(vs.x); a[1] += bfhi(vs.x); a[2] += bflo(vs.y); a[3] += bfhi(vs.y);
        float dn = dinv[n];
        acc0 += a[0] * dn + bs0;
        acc1 += a[1] * dn + bs1;
        acc2 += a[2] * dn + bs2;
        acc3 += a[3] * dn + bs3;
    }
    if (half == 0) {
        float* pp = &pooled[(size_t)gcur * F_CAT + pcol];
        unsafeAtomicAdd(pp,     acc0);
        unsafeAtomicAdd(pp + 1, acc1);
        unsafeAtomicAdd(pp + 2, acc2);
        unsafeAtomicAdd(pp + 3, acc3);
    }
}

// ---------------------------------------------------------------------------
__global__ __launch_bounds__(256) void mlp_kernel(const float* __restrict__ pooled,
                                                  const float* __restrict__ pw1,
                                                  const float* __restrict__ pb1,
                                                  const float* __restrict__ pw2,
                                                  const float* __restrict__ pb2,
                                                  float* __restrict__ out) {
    int g = blockIdx.x;
    int tid = threadIdx.x;
    __shared__ float row[256];
    __shared__ float hid[256];
    row[tid] = pooled[(size_t)g * 256 + tid];
    __syncthreads();
    float acc = pb1[tid];
    for (int k = 0; k < 256; k++) acc += row[k] * pw1[(size_t)k * 256 + tid];
    hid[tid] = fmaxf(acc, 0.f);
    __syncthreads();
    if (tid < 128) {
        float o = pb2[tid];
        for (int k = 0; k < 256; k++) o += hid[k] * pw2[(size_t)k * 128 + tid];
        out[(size_t)g * 128 + tid] = o;
    }
}

// ---------------------------------------------------------------------------
extern "C" void kernel_launch(void* const* d_in, const int* in_sizes, int n_in,
                              void* d_out, int out_size, void* d_ws, size_t ws_size,
                              hipStream_t stream) {
    const float* x     = (const float*)d_in[0];
    const int*   ei    = (const int*)d_in[1];
    const int*   batch = (const int*)d_in[2];
    const float* td_W1 = (const float*)d_in[4];
    const float* td_b1 = (const float*)d_in[5];
    const float* td_W2 = (const float*)d_in[6];
    const float* td_b2 = (const float*)d_in[7];
    const float* bu_W1 = (const float*)d_in[8];
    const float* bu_b1 = (const float*)d_in[9];
    const float* bu_W2 = (const float*)d_in[10];
    const float* bu_b2 = (const float*)d_in[11];
    const float* pw1   = (const float*)d_in[12];
    const float* pb1   = (const float*)d_in[13];
    const float* pw2   = (const float*)d_in[14];
    const float* pb2   = (const float*)d_in[15];
    float* out = (float*)d_out;

    // ---- workspace carve ----
    char* p = (char*)d_ws;
    auto alloc = [&](size_t bytes) { void* r = (void*)p; p += (bytes + 255) & ~(size_t)255; return r; };
    // single memset region: gcur (1 KB) + pooled (512 KB)
    char* zreg = (char*)alloc(1024 + (size_t)N_GRAPHS * F_CAT * sizeof(float));
    int* gcur = (int*)zreg;
    float* pooled = (float*)(zreg + 1024);
    uint* ebuf_td = (uint*)alloc((size_t)NB * CAP * sizeof(uint));
    uint* ebuf_bu = (uint*)alloc((size_t)NB * CAP * sizeof(uint));
    ushort* csr_td = (ushort*)alloc((size_t)NB * CAP * sizeof(ushort));
    ushort* csr_bu = (ushort*)alloc((size_t)NB * CAP * sizeof(ushort));
    int* off_td = (int*)alloc((size_t)N_NODES * sizeof(int));
    int* off_bu = (int*)alloc((size_t)N_NODES * sizeof(int));
    ushort* deg_td = (ushort*)alloc((size_t)N_NODES * sizeof(ushort));
    ushort* deg_bu = (ushort*)alloc((size_t)N_NODES * sizeof(ushort));
    float* dinv_td = (float*)alloc((size_t)N_PAD * sizeof(float));
    float* dinv_bu = (float*)alloc((size_t)N_PAD * sizeof(float));
    ushort* Bt1 = (ushort*)alloc((size_t)256 * 256 * sizeof(ushort));
    ushort* Bt2 = (ushort*)alloc((size_t)256 * 128 * sizeof(ushort));
    ushort* xb   = (ushort*)alloc((size_t)N_PAD * F_CAT * sizeof(ushort));
    ushort* linb = (ushort*)alloc((size_t)N_PAD * F_CAT * sizeof(ushort));
    ushort* h1b  = (ushort*)alloc((size_t)N_PAD * F_CAT * sizeof(ushort));

    hipMemsetAsync(zreg, 0, 1024 + (size_t)N_GRAPHS * F_CAT * sizeof(float), stream);

    // ---- graph structure (bucketed counting sort) ----
    csr_scatter_kernel<<<N_EDGES / EPB, 256, 0, stream>>>(ei, gcur, ebuf_td, ebuf_bu);
    csr_build_kernel<<<dim3(NB, 2), 256, 0, stream>>>(ebuf_td, ebuf_bu, gcur,
        off_td, off_bu, deg_td, deg_bu, dinv_td, dinv_bu, csr_td, csr_bu);

    // ---- bf16 conversions ----
    cvt_x_kernel<<<(N_PAD * F_IN / 4) / 256, 256, 0, stream>>>(x, xb);
    prep_w_kernel<<<256, 256, 0, stream>>>(td_W1, bu_W1, td_W2, bu_W2, Bt1, Bt2);

    dim3 gg(N_PAD / 128, 2);

    // ---- layer 1 ----
    gemm_mfma<<<gg, 256, 0, stream>>>(xb, Bt1, linb, dinv_td, dinv_bu, 256, 256, 0);
    agg1_kernel<<<N_NODES / 2, 256, 0, stream>>>(linb, h1b,
        csr_td, off_td, deg_td, dinv_td, csr_bu, off_bu, deg_bu, dinv_bu, td_b1, bu_b1);

    // ---- layer 2 (block-diagonal -> K=128 split) + pool ----
    gemm_mfma<<<gg, 256, 0, stream>>>(h1b, Bt2, linb, dinv_td, dinv_bu, 128, 128, 1);
    agg2_pool_kernel<<<N_NODES / 16, 256, 0, stream>>>(linb, pooled, batch,
        csr_td, off_td, deg_td, dinv_td, csr_bu, off_bu, deg_bu, dinv_bu, td_b2, bu_b2);

    // ---- projection head ----
    mlp_kernel<<<N_GRAPHS, 256, 0, stream>>>(pooled, pw1, pb1, pw2, pb2, out);
}

// Round 7
// 351.660 us; speedup vs baseline: 1.6820x; 1.0262x over previous
//
#include <hip/hip_runtime.h>

#define N_NODES 50000
#define N_PAD   50048   // 391*128, GEMM drops all row guards
#define N_EDGES 800000
#define N_GRAPHS 512
#define F_IN 256
#define F_H 128
#define F_CAT 256

// bucketed CSR build
#define BSHIFT 9
#define NB 98           // ceil(50000/512) buckets
#define CAP 10240       // edge capacity per bucket (mean 8163, 23 sigma slack)
#define EPB 3125        // edges per scatter block (256 blocks)

typedef __attribute__((ext_vector_type(8))) short short8;
typedef __attribute__((ext_vector_type(4))) float f32x4;
typedef unsigned int uint;
typedef unsigned short ushort;

static __device__ __forceinline__ ushort f2bf(float f) {
    uint u = __float_as_uint(f);
    u += 0x7FFF + ((u >> 16) & 1);  // RNE
    return (ushort)(u >> 16);
}
static __device__ __forceinline__ float bflo(uint v) { return __uint_as_float(v << 16); }
static __device__ __forceinline__ float bfhi(uint v) { return __uint_as_float(v & 0xFFFF0000u); }
static __device__ __forceinline__ float bfu(ushort v) { return __uint_as_float((uint)v << 16); }

// async global->LDS, 16B per lane; lds base must be wave-uniform
#define GLL(g, l) __builtin_amdgcn_global_load_lds( \
    (const __attribute__((address_space(1))) unsigned int*)(g), \
    (__attribute__((address_space(3))) unsigned int*)(l), 16, 0, 0)

// ---------------------------------------------------------------------------
// S1: bucket-scatter edges. gcur is RELATIVE (zero-initialized by memset).
__global__ __launch_bounds__(256) void csr_scatter_kernel(
        const int* __restrict__ ei, int* __restrict__ gcur,
        uint* __restrict__ ebuf_td, uint* __restrict__ ebuf_bu) {
    __shared__ int lcnt[256];   // [dir*128 + bucket]
    __shared__ int lbase[256];
    int tid = threadIdx.x;
    lcnt[tid] = 0;
    __syncthreads();
    int e0 = blockIdx.x * EPB;
    for (int k = tid; k < EPB; k += 256) {
        int i = e0 + k;
        int s = ei[i], d = ei[N_EDGES + i];
        atomicAdd(&lcnt[d >> BSHIFT], 1);
        atomicAdd(&lcnt[128 + (s >> BSHIFT)], 1);
    }
    __syncthreads();
    if (tid < 2 * NB) {
        int dir = tid / NB, b = tid % NB;
        int c = lcnt[dir * 128 + b];
        lbase[dir * 128 + b] = c ? atomicAdd(&gcur[dir * NB + b], c) : 0;
    }
    __syncthreads();
    lcnt[tid] = 0;
    __syncthreads();
    for (int k = tid; k < EPB; k += 256) {
        int i = e0 + k;
        int s = ei[i], d = ei[N_EDGES + i];
        int bd = d >> BSHIFT, bs = s >> BSHIFT;
        int p = atomicAdd(&lcnt[bd], 1) + lbase[bd];
        ebuf_td[(size_t)bd * CAP + p] = (uint)s | ((uint)(d & 511) << 16);
        int q = atomicAdd(&lcnt[128 + bs], 1) + lbase[128 + bs];
        ebuf_bu[(size_t)bs * CAP + q] = (uint)d | ((uint)(s & 511) << 16);
    }
}

// ---------------------------------------------------------------------------
// S2: per-(bucket,dir) CSR build, bucket-local scatter window
__global__ __launch_bounds__(256) void csr_build_kernel(
        const uint* __restrict__ ebuf_td, const uint* __restrict__ ebuf_bu,
        const int* __restrict__ gcur,
        int* off_td, int* off_bu, ushort* deg_td, ushort* deg_bu,
        float* dinv_td, float* dinv_bu, ushort* csr_td, ushort* csr_bu) {
    int b = blockIdx.x, dir = blockIdx.y;
    const uint* ebuf = dir ? ebuf_bu : ebuf_td;
    int* off     = dir ? off_bu : off_td;
    ushort* deg  = dir ? deg_bu : deg_td;
    float* dinv  = dir ? dinv_bu : dinv_td;
    ushort* csr  = dir ? csr_bu : csr_td;
    __shared__ int cntL[512], offL[512], sm[256];
    int tid = threadIdx.x;
    cntL[tid] = 0; cntL[tid + 256] = 0;
    __syncthreads();
    int rbeg = b * CAP;
    int rend = rbeg + gcur[dir * NB + b];
    for (int k = rbeg + tid; k < rend; k += 256)
        atomicAdd(&cntL[ebuf[k] >> 16], 1);
    __syncthreads();
    int a0 = cntL[tid * 2], a1 = cntL[tid * 2 + 1];
    int ps = a0 + a1;
    sm[tid] = ps;
    __syncthreads();
    for (int o = 1; o < 256; o <<= 1) {
        int u = (tid >= o) ? sm[tid - o] : 0;
        __syncthreads();
        sm[tid] += u;
        __syncthreads();
    }
    int excl = sm[tid] - ps;
    offL[tid * 2] = excl;
    offL[tid * 2 + 1] = excl + a0;
    __syncthreads();
    int nbase = b << BSHIFT;
#pragma unroll
    for (int j = 0; j < 2; j++) {
        int nloc = tid + j * 256;
        int n = nbase + nloc;
        if (n < N_NODES) {
            off[n] = rbeg + offL[nloc];
            int c = cntL[nloc];
            deg[n] = (ushort)c;
            dinv[n] = rsqrtf((float)c + 1.0f);
        }
    }
    cntL[tid] = offL[tid];
    cntL[tid + 256] = offL[tid + 256];
    __syncthreads();
    for (int k = rbeg + tid; k < rend; k += 256) {
        uint e = ebuf[k];
        int slot = atomicAdd(&cntL[e >> 16], 1);
        csr[rbeg + slot] = (ushort)(e & 0xFFFF);
    }
}

// ---------------------------------------------------------------------------
__global__ void cvt_x_kernel(const float* __restrict__ x, ushort* __restrict__ xb) {
    size_t i = (size_t)blockIdx.x * blockDim.x + threadIdx.x;  // float4 index
    ushort4 u = {0, 0, 0, 0};
    if (i < (size_t)N_NODES * (F_IN / 4)) {
        float4 f = ((const float4*)x)[i];
        u.x = f2bf(f.x); u.y = f2bf(f.y); u.z = f2bf(f.z); u.w = f2bf(f.w);
    }
    ((ushort4*)xb)[i] = u;
}

// ---------------------------------------------------------------------------
// Bt1[n][k] (n=out col of layer-1 concat, k=0..255).
// Wt2[k][c]: head weight, c = output index in concat([bu, td]) order:
//   c<128 -> bu_W2[k][c], c>=128 -> td_W2[k][c-128]; k in [0,128).
__global__ void prep_w_kernel(const float* __restrict__ td_W1, const float* __restrict__ bu_W1,
                              const float* __restrict__ td_W2, const float* __restrict__ bu_W2,
                              ushort* __restrict__ Bt1, ushort* __restrict__ Wt2) {
    int n = blockIdx.x;   // 0..255
    int k = threadIdx.x;  // 0..255
    float w1 = (n < F_H) ? td_W1[(size_t)k * F_H + n] : bu_W1[(size_t)k * F_H + (n - F_H)];
    Bt1[(size_t)n * 256 + k] = f2bf(w1);
    if (k < 128) {
        float w2 = (n < F_H) ? bu_W2[(size_t)k * F_H + n]
                             : td_W2[(size_t)k * F_H + (n - F_H)];
        Wt2[(size_t)k * 256 + n] = f2bf(w2);
    }
}

// ---------------------------------------------------------------------------
// MFMA GEMM (layer 1 only): C = A[M,256] @ Bt1^T, row scaled by branch dinv,
// bf16 out. 128x128 tile, BK=32, 256 thr / 4 waves.
__global__ __launch_bounds__(256) void gemm_mfma(
        const ushort* __restrict__ A, const ushort* __restrict__ Bt,
        ushort* __restrict__ C,
        const float* __restrict__ dinv_td, const float* __restrict__ dinv_bu) {
    __shared__ __align__(16) ushort As[128 * 32];
    __shared__ __align__(16) ushort Bs[128 * 32];
    int tid = threadIdx.x;
    int wave = tid >> 6, lane = tid & 63, quad = lane >> 4, l16 = lane & 15;
    size_t bm = (size_t)blockIdx.x * 128;
    size_t bn = (size_t)blockIdx.y * 128;
    const float* dsel = blockIdx.y ? dinv_bu : dinv_td;

    f32x4 acc[2][8];
    const f32x4 z4 = {0.f, 0.f, 0.f, 0.f};
#pragma unroll
    for (int i = 0; i < 2; i++)
#pragma unroll
        for (int j = 0; j < 8; j++) acc[i][j] = z4;

    int cb0 = wave * 64;
    int cb1 = 256 + wave * 64;
    int c0 = cb0 + lane, c1 = cb1 + lane;
    int r0 = c0 >> 2, s0 = (c0 & 3) * 8;
    int r1 = c1 >> 2, s1 = (c1 & 3) * 8;
    const ushort* a0p = A + (bm + r0) * 256 + s0;
    const ushort* a1p = A + (bm + r1) * 256 + s1;
    const ushort* b0p = Bt + (bn + r0) * 256 + s0;
    const ushort* b1p = Bt + (bn + r1) * 256 + s1;
    ushort* lA0 = As + cb0 * 8;
    ushort* lA1 = As + cb1 * 8;
    ushort* lB0 = Bs + cb0 * 8;
    ushort* lB1 = Bs + cb1 * 8;

    for (int kb = 0; kb < 8; kb++) {
        int k0 = kb * 32;
        __syncthreads();
        GLL(a0p + k0, lA0);
        GLL(a1p + k0, lA1);
        GLL(b0p + k0, lB0);
        GLL(b1p + k0, lB1);
        __syncthreads();
        short8 af0 = *(const short8*)(As + (wave * 32 + l16) * 32 + quad * 8);
        short8 af1 = *(const short8*)(As + (wave * 32 + 16 + l16) * 32 + quad * 8);
#pragma unroll
        for (int ct = 0; ct < 8; ct++) {
            short8 bfr = *(const short8*)(Bs + (ct * 16 + l16) * 32 + quad * 8);
            acc[0][ct] = __builtin_amdgcn_mfma_f32_16x16x32_bf16(af0, bfr, acc[0][ct], 0, 0, 0);
            acc[1][ct] = __builtin_amdgcn_mfma_f32_16x16x32_bf16(af1, bfr, acc[1][ct], 0, 0, 0);
        }
    }
#pragma unroll
    for (int rt = 0; rt < 2; rt++) {
#pragma unroll
        for (int r = 0; r < 4; r++) {
            size_t row = bm + wave * 32 + rt * 16 + quad * 4 + r;
            float dv = dsel[row];
#pragma unroll
            for (int ct = 0; ct < 8; ct++) {
                C[row * 256 + bn + ct * 16 + l16] = f2bf(acc[rt][ct][r] * dv);
            }
        }
    }
}

// ---------------------------------------------------------------------------
// Wave-gather: lane = half*32 + l32; l32 covers 4 cols (uint2), half selects
// one of 2 concurrent edge rows. Unroll-8 -> 16 edges in flight per wave.
static __device__ __forceinline__ void gather_node(
        const ushort* __restrict__ base, const ushort* __restrict__ csr,
        int kb, int ke, int half, float a[4]) {
    float p[4] = {0.f, 0.f, 0.f, 0.f};
    float q[4] = {0.f, 0.f, 0.f, 0.f};
    float r[4] = {0.f, 0.f, 0.f, 0.f};
    int k = kb;
    for (; k + 16 <= ke; k += 16) {
        int i0 = csr[k + half],      i1 = csr[k + 2 + half];
        int i2 = csr[k + 4 + half],  i3 = csr[k + 6 + half];
        int i4 = csr[k + 8 + half],  i5 = csr[k + 10 + half];
        int i6 = csr[k + 12 + half], i7 = csr[k + 14 + half];
        uint2 v0 = *(const uint2*)(base + (size_t)i0 * F_CAT);
        uint2 v1 = *(const uint2*)(base + (size_t)i1 * F_CAT);
        uint2 v2 = *(const uint2*)(base + (size_t)i2 * F_CAT);
        uint2 v3 = *(const uint2*)(base + (size_t)i3 * F_CAT);
        uint2 v4 = *(const uint2*)(base + (size_t)i4 * F_CAT);
        uint2 v5 = *(const uint2*)(base + (size_t)i5 * F_CAT);
        uint2 v6 = *(const uint2*)(base + (size_t)i6 * F_CAT);
        uint2 v7 = *(const uint2*)(base + (size_t)i7 * F_CAT);
        a[0] += bflo(v0.x); a[1] += bfhi(v0.x); a[2] += bflo(v0.y); a[3] += bfhi(v0.y);
        p[0] += bflo(v1.x); p[1] += bfhi(v1.x); p[2] += bflo(v1.y); p[3] += bfhi(v1.y);
        q[0] += bflo(v2.x); q[1] += bfhi(v2.x); q[2] += bflo(v2.y); q[3] += bfhi(v2.y);
        r[0] += bflo(v3.x); r[1] += bfhi(v3.x); r[2] += bflo(v3.y); r[3] += bfhi(v3.y);
        a[0] += bflo(v4.x); a[1] += bfhi(v4.x); a[2] += bflo(v4.y); a[3] += bfhi(v4.y);
        p[0] += bflo(v5.x); p[1] += bfhi(v5.x); p[2] += bflo(v5.y); p[3] += bfhi(v5.y);
        q[0] += bflo(v6.x); q[1] += bfhi(v6.x); q[2] += bflo(v6.y); q[3] += bfhi(v6.y);
        r[0] += bflo(v7.x); r[1] += bfhi(v7.x); r[2] += bflo(v7.y); r[3] += bfhi(v7.y);
    }
    for (; k + 8 <= ke; k += 8) {
        int i0 = csr[k + half],     i1 = csr[k + 2 + half];
        int i2 = csr[k + 4 + half], i3 = csr[k + 6 + half];
        uint2 v0 = *(const uint2*)(base + (size_t)i0 * F_CAT);
        uint2 v1 = *(const uint2*)(base + (size_t)i1 * F_CAT);
        uint2 v2 = *(const uint2*)(base + (size_t)i2 * F_CAT);
        uint2 v3 = *(const uint2*)(base + (size_t)i3 * F_CAT);
        a[0] += bflo(v0.x); a[1] += bfhi(v0.x); a[2] += bflo(v0.y); a[3] += bfhi(v0.y);
        p[0] += bflo(v1.x); p[1] += bfhi(v1.x); p[2] += bflo(v1.y); p[3] += bfhi(v1.y);
        q[0] += bflo(v2.x); q[1] += bfhi(v2.x); q[2] += bflo(v2.y); q[3] += bfhi(v2.y);
        r[0] += bflo(v3.x); r[1] += bfhi(v3.x); r[2] += bflo(v3.y); r[3] += bfhi(v3.y);
    }
    for (; k < ke; k += 2) {
        int kk = k + half;
        if (kk < ke) {
            uint2 v = *(const uint2*)(base + (size_t)csr[kk] * F_CAT);
            a[0] += bflo(v.x); a[1] += bfhi(v.x); a[2] += bflo(v.y); a[3] += bfhi(v.y);
        }
    }
#pragma unroll
    for (int j = 0; j < 4; j++) a[j] += (p[j] + q[j]) + r[j];
}

// ---------------------------------------------------------------------------
// Layer-1 aggregation. Wave handles 8 consecutive nodes of one branch.
// h1s[n] = relu(dn*(self+neigh) + b1) * dn   (dinv pre-folded for layer 2)
__global__ __launch_bounds__(256) void agg1_kernel(
        const ushort* __restrict__ linS, ushort* __restrict__ h1s,
        const ushort* __restrict__ csr_td, const int* __restrict__ off_td,
        const ushort* __restrict__ deg_td, const float* __restrict__ dinv_td,
        const ushort* __restrict__ csr_bu, const int* __restrict__ off_bu,
        const ushort* __restrict__ deg_bu, const float* __restrict__ dinv_bu,
        const float* __restrict__ b_td, const float* __restrict__ b_bu) {
    int wave = threadIdx.x >> 6, lane = threadIdx.x & 63;
    int n0 = (blockIdx.x * 2 + (wave >> 1)) * 8;
    int br = wave & 1;
    const ushort* csr = br ? csr_bu : csr_td;
    const int* off    = br ? off_bu : off_td;
    const ushort* deg = br ? deg_bu : deg_td;
    const float* dinv = br ? dinv_bu : dinv_td;
    const float* bias = br ? b_bu : b_td;
    int half = lane >> 5, l32 = lane & 31;
    int col = br * F_H + l32 * 4;
    const ushort* base = linS + col;
    int bcol = l32 * 4;
    float bs0 = bias[bcol], bs1 = bias[bcol + 1];
    float bs2 = bias[bcol + 2], bs3 = bias[bcol + 3];

#pragma unroll
    for (int j = 0; j < 8; j++) {
        int n = n0 + j;
        float a[4] = {0.f, 0.f, 0.f, 0.f};
        int kb = off[n];
        gather_node(base, csr, kb, kb + deg[n], half, a);
#pragma unroll
        for (int t = 0; t < 4; t++) a[t] += __shfl_xor(a[t], 32);
        uint2 vs = *(const uint2*)(base + (size_t)n * F_CAT);  // self
        a[0] += bflo(vs.x); a[1] += bfhi(vs.x); a[2] += bflo(vs.y); a[3] += bfhi(vs.y);
        float dn = dinv[n];
        float o0 = fmaxf(a[0] * dn + bs0, 0.f) * dn;
        float o1 = fmaxf(a[1] * dn + bs1, 0.f) * dn;
        float o2 = fmaxf(a[2] * dn + bs2, 0.f) * dn;
        float o3 = fmaxf(a[3] * dn + bs3, 0.f) * dn;
        if (half == 0) {
            uint2 pk;
            pk.x = (uint)f2bf(o0) | ((uint)f2bf(o1) << 16);
            pk.y = (uint)f2bf(o2) | ((uint)f2bf(o3) << 16);
            *(uint2*)(h1s + (size_t)n * F_CAT + col) = pk;
        }
    }
}

// ---------------------------------------------------------------------------
// Layer-2 aggregation fused with pooling (pool-before-W2 algebra):
// pooled_pre[g, col] += dn*(self + neigh) over nodes of graph g.
// Layout: cols [0:128)=td, [128:256)=bu (natural h1s layout).
__global__ __launch_bounds__(256) void agg2_pool_kernel(
        const ushort* __restrict__ h1s, float* __restrict__ pooled_pre,
        const int* __restrict__ batch,
        const ushort* __restrict__ csr_td, const int* __restrict__ off_td,
        const ushort* __restrict__ deg_td, const float* __restrict__ dinv_td,
        const ushort* __restrict__ csr_bu, const int* __restrict__ off_bu,
        const ushort* __restrict__ deg_bu, const float* __restrict__ dinv_bu) {
    int wave = threadIdx.x >> 6, lane = threadIdx.x & 63;
    int n0 = (blockIdx.x * 2 + (wave >> 1)) * 8;
    int br = wave & 1;
    const ushort* csr = br ? csr_bu : csr_td;
    const int* off    = br ? off_bu : off_td;
    const ushort* deg = br ? deg_bu : deg_td;
    const float* dinv = br ? dinv_bu : dinv_td;
    int half = lane >> 5, l32 = lane & 31;
    int col = br * F_H + l32 * 4;
    const ushort* base = h1s + col;

    float acc0 = 0.f, acc1 = 0.f, acc2 = 0.f, acc3 = 0.f;
    int gcur = batch[n0];
#pragma unroll
    for (int j = 0; j < 8; j++) {
        int n = n0 + j;
        int g = batch[n];
        if (g != gcur) {  // wave-uniform
            if (half == 0) {
                float* pp = &pooled_pre[(size_t)gcur * F_CAT + col];
                unsafeAtomicAdd(pp,     acc0);
                unsafeAtomicAdd(pp + 1, acc1);
                unsafeAtomicAdd(pp + 2, acc2);
                unsafeAtomicAdd(pp + 3, acc3);
            }
            acc0 = acc1 = acc2 = acc3 = 0.f;
            gcur = g;
        }
        float a[4] = {0.f, 0.f, 0.f, 0.f};
        int kb = off[n];
        gather_node(base, csr, kb, kb + deg[n], half, a);
#pragma unroll
        for (int t = 0; t < 4; t++) a[t] += __shfl_xor(a[t], 32);
        uint2 vs = *(const uint2*)(base + (size_t)n * F_CAT);
        a[0] += bflo(vs.x); a[1] += bfhi(vs.x); a[2] += bflo(vs.y); a[3] += bfhi(vs.y);
        float dn = dinv[n];
        acc0 += a[0] * dn;
        acc1 += a[1] * dn;
        acc2 += a[2] * dn;
        acc3 += a[3] * dn;
    }
    if (half == 0) {
        float* pp = &pooled_pre[(size_t)gcur * F_CAT + col];
        unsafeAtomicAdd(pp,     acc0);
        unsafeAtomicAdd(pp + 1, acc1);
        unsafeAtomicAdd(pp + 2, acc2);
        unsafeAtomicAdd(pp + 3, acc3);
    }
}

// ---------------------------------------------------------------------------
// Head: per graph, z = concat([bu,td]) = pooled_pre @ W2 (per branch) + cnt*b2,
// then MLP relu(z@pw1+pb1)@pw2+pb2. One block per graph.
__global__ __launch_bounds__(256) void head_kernel(
        const float* __restrict__ pooled_pre, const int* __restrict__ batch,
        const ushort* __restrict__ Wt2,
        const float* __restrict__ td_b2, const float* __restrict__ bu_b2,
        const float* __restrict__ pw1, const float* __restrict__ pb1,
        const float* __restrict__ pw2, const float* __restrict__ pb2,
        float* __restrict__ out) {
    int g = blockIdx.x;
    int tid = threadIdx.x;
    __shared__ float row[256], z[256], hid[256];
    row[tid] = pooled_pre[(size_t)g * 256 + tid];
    // node count of graph g (sorted batch, binary search; broadcast loads)
    int lo = 0, hi = N_NODES;
    while (lo < hi) { int m = (lo + hi) >> 1; if (batch[m] < g) lo = m + 1; else hi = m; }
    int start = lo;
    lo = start; hi = N_NODES;
    while (lo < hi) { int m = (lo + hi) >> 1; if (batch[m] < g + 1) lo = m + 1; else hi = m; }
    float cnt = (float)(lo - start);
    __syncthreads();
    // z[c]: c<128 -> bu (uses row[128..]), c>=128 -> td (uses row[0..])
    const float* rsel = (tid < 128) ? (row + F_H) : row;
    float b2 = (tid < 128) ? bu_b2[tid] : td_b2[tid - F_H];
    float acc = cnt * b2;
    for (int k = 0; k < F_H; k++) acc += rsel[k] * bfu(Wt2[(size_t)k * 256 + tid]);
    z[tid] = acc;
    __syncthreads();
    float h = pb1[tid];
    for (int k = 0; k < 256; k++) h += z[k] * pw1[(size_t)k * 256 + tid];
    hid[tid] = fmaxf(h, 0.f);
    __syncthreads();
    if (tid < 128) {
        float o = pb2[tid];
        for (int k = 0; k < 256; k++) o += hid[k] * pw2[(size_t)k * 128 + tid];
        out[(size_t)g * 128 + tid] = o;
    }
}

// ---------------------------------------------------------------------------
extern "C" void kernel_launch(void* const* d_in, const int* in_sizes, int n_in,
                              void* d_out, int out_size, void* d_ws, size_t ws_size,
                              hipStream_t stream) {
    const float* x     = (const float*)d_in[0];
    const int*   ei    = (const int*)d_in[1];
    const int*   batch = (const int*)d_in[2];
    const float* td_W1 = (const float*)d_in[4];
    const float* td_b1 = (const float*)d_in[5];
    const float* td_W2 = (const float*)d_in[6];
    const float* td_b2 = (const float*)d_in[7];
    const float* bu_W1 = (const float*)d_in[8];
    const float* bu_b1 = (const float*)d_in[9];
    const float* bu_W2 = (const float*)d_in[10];
    const float* bu_b2 = (const float*)d_in[11];
    const float* pw1   = (const float*)d_in[12];
    const float* pb1   = (const float*)d_in[13];
    const float* pw2   = (const float*)d_in[14];
    const float* pb2   = (const float*)d_in[15];
    float* out = (float*)d_out;

    // ---- workspace carve ----
    char* p = (char*)d_ws;
    auto alloc = [&](size_t bytes) { void* r = (void*)p; p += (bytes + 255) & ~(size_t)255; return r; };
    // single memset region: gcur (1 KB) + pooled_pre (512 KB)
    char* zreg = (char*)alloc(1024 + (size_t)N_GRAPHS * F_CAT * sizeof(float));
    int* gcur = (int*)zreg;
    float* pooled_pre = (float*)(zreg + 1024);
    uint* ebuf_td = (uint*)alloc((size_t)NB * CAP * sizeof(uint));
    uint* ebuf_bu = (uint*)alloc((size_t)NB * CAP * sizeof(uint));
    ushort* csr_td = (ushort*)alloc((size_t)NB * CAP * sizeof(ushort));
    ushort* csr_bu = (ushort*)alloc((size_t)NB * CAP * sizeof(ushort));
    int* off_td = (int*)alloc((size_t)N_NODES * sizeof(int));
    int* off_bu = (int*)alloc((size_t)N_NODES * sizeof(int));
    ushort* deg_td = (ushort*)alloc((size_t)N_NODES * sizeof(ushort));
    ushort* deg_bu = (ushort*)alloc((size_t)N_NODES * sizeof(ushort));
    float* dinv_td = (float*)alloc((size_t)N_PAD * sizeof(float));
    float* dinv_bu = (float*)alloc((size_t)N_PAD * sizeof(float));
    ushort* Bt1 = (ushort*)alloc((size_t)256 * 256 * sizeof(ushort));
    ushort* Wt2 = (ushort*)alloc((size_t)128 * 256 * sizeof(ushort));
    ushort* xb   = (ushort*)alloc((size_t)N_PAD * F_CAT * sizeof(ushort));
    ushort* linb = (ushort*)alloc((size_t)N_PAD * F_CAT * sizeof(ushort));
    ushort* h1s  = (ushort*)alloc((size_t)N_PAD * F_CAT * sizeof(ushort));

    hipMemsetAsync(zreg, 0, 1024 + (size_t)N_GRAPHS * F_CAT * sizeof(float), stream);

    // ---- graph structure (bucketed counting sort) ----
    csr_scatter_kernel<<<N_EDGES / EPB, 256, 0, stream>>>(ei, gcur, ebuf_td, ebuf_bu);
    csr_build_kernel<<<dim3(NB, 2), 256, 0, stream>>>(ebuf_td, ebuf_bu, gcur,
        off_td, off_bu, deg_td, deg_bu, dinv_td, dinv_bu, csr_td, csr_bu);

    // ---- bf16 conversions ----
    cvt_x_kernel<<<(N_PAD * F_IN / 4) / 256, 256, 0, stream>>>(x, xb);
    prep_w_kernel<<<256, 256, 0, stream>>>(td_W1, bu_W1, td_W2, bu_W2, Bt1, Wt2);

    // ---- layer 1: GEMM + aggregation ----
    dim3 gg(N_PAD / 128, 2);
    gemm_mfma<<<gg, 256, 0, stream>>>(xb, Bt1, linb, dinv_td, dinv_bu);
    agg1_kernel<<<N_NODES / 16, 256, 0, stream>>>(linb, h1s,
        csr_td, off_td, deg_td, dinv_td, csr_bu, off_bu, deg_bu, dinv_bu, td_b1, bu_b1);

    // ---- layer 2: aggregation+pool (W2 deferred to head) ----
    agg2_pool_kernel<<<N_NODES / 16, 256, 0, stream>>>(h1s, pooled_pre, batch,
        csr_td, off_td, deg_td, dinv_td, csr_bu, off_bu, deg_bu, dinv_bu);

    // ---- head: W2 matvec + cnt*b2 + MLP ----
    head_kernel<<<N_GRAPHS, 256, 0, stream>>>(pooled_pre, batch, Wt2,
        td_b2, bu_b2, pw1, pb1, pw2, pb2, out);
}